// Round 1
// baseline (23770.239 us; speedup 1.0000x reference)
//
#include <hip/hip_runtime.h>
#include <hip/hip_bf16.h>

typedef __bf16 bf16x8 __attribute__((ext_vector_type(8)));
typedef float  f32x4  __attribute__((ext_vector_type(4)));

static __device__ __forceinline__ f32x4 mfma16(bf16x8 a, bf16x8 b, f32x4 c) {
    return __builtin_amdgcn_mfma_f32_16x16x32_bf16(a, b, c, 0, 0, 0);
}

#define BTOT 256
#define TLEN 512
#define IDIM 128
#define FDIM 512
#define MDIM 512
#define ODIM 128
#define BC   16
#define NWG  16
#define K1   (IDIM + MDIM)          // 640
#define K2   (MDIM + FDIM)          // 1024
#define ACOLS (IDIM + MDIM + FDIM)  // 1152
#define ASTR  (ACOLS + 8)           // 1160 (pad -> 2-way-free LDS banking)

#define N_W1  (FDIM * K1)           // 327680
#define N_W23 (MDIM * K2)           // 524288
#define N_WO  (ODIM * MDIM)         // 65536

// ws byte offsets
#define WS_W1   0
#define WS_W23  (N_W1 * 2)
#define WS_WO   (WS_W23 + N_W23 * 2)
#define WS_B1   (WS_WO + N_WO * 2)
#define WS_B23  (WS_B1 + FDIM * 4)

// ---------------------------------------------------------------------------
// Prep: pack concatenated bf16 weights + fused biases into workspace.
//   W1[f][k]  = k<128 ? Wi2f[f][k] : Wm2f[f][k-128]          (512 x 640)
//   W23[m][k] = k<512 ? Wm2m[m][k] : Wf2m[m][k-512]          (512 x 1024)
//   Wo[o][k]  = Wout[o][k]                                   (128 x 512)
//   b1 = bi2f + bm2f ; b23 = bf2m + bm2m
// ---------------------------------------------------------------------------
__global__ __launch_bounds__(256) void lmn_prep(
    const float* __restrict__ Wi2f, const float* __restrict__ Wm2f,
    const float* __restrict__ Wf2m, const float* __restrict__ Wm2m,
    const float* __restrict__ Wout,
    const float* __restrict__ bi2f, const float* __restrict__ bm2f,
    const float* __restrict__ bf2m, const float* __restrict__ bm2m,
    __bf16* __restrict__ W1, __bf16* __restrict__ W23, __bf16* __restrict__ Wo,
    float* __restrict__ b1, float* __restrict__ b23)
{
    int i = blockIdx.x * 256 + threadIdx.x;
    if (i < N_W1) {
        int f = i / K1, k = i - f * K1;
        float v = (k < IDIM) ? Wi2f[f * IDIM + k] : Wm2f[f * MDIM + (k - IDIM)];
        W1[i] = (__bf16)v;
        return;
    }
    i -= N_W1;
    if (i < N_W23) {
        int mo = i / K2, k = i - mo * K2;
        float v = (k < MDIM) ? Wm2m[mo * MDIM + k] : Wf2m[mo * FDIM + (k - MDIM)];
        W23[i] = (__bf16)v;
        return;
    }
    i -= N_W23;
    if (i < N_WO) { Wo[i] = (__bf16)Wout[i]; return; }
    i -= N_WO;
    if (i < FDIM) { b1[i] = bi2f[i] + bm2f[i]; return; }
    i -= FDIM;
    if (i < MDIM) { b23[i] = bf2m[i] + bm2m[i]; return; }
}

// ---------------------------------------------------------------------------
// Persistent scan kernel: 16 WGs x 1024 threads (16 waves). WG g owns batch
// rows 16g..16g+15 and runs all 512 timesteps with intra-WG barriers only.
// LDS activation buffer per row: [ x_t (128) | m (512) | f (512) ] bf16.
//   G1 : A = cols 0:640  (=[x|m]),  B = W1  -> f   (tanh, bias fused)
//   G23: A = cols 128:1152 (=[m|f]), B = W23 -> m'  (bias fused)
// B-fragments stream straight from L2 (row-major packed weights, 16B/lane).
// ---------------------------------------------------------------------------
__global__ __launch_bounds__(1024) void lmn_scan(
    const float* __restrict__ x, const float* __restrict__ m0,
    const __bf16* __restrict__ W1, const __bf16* __restrict__ W23,
    const __bf16* __restrict__ Wo,
    const float* __restrict__ b1, const float* __restrict__ b23,
    const float* __restrict__ bout, float* __restrict__ out)
{
    __shared__ __bf16 A[BC][ASTR];

    const int tid  = threadIdx.x;
    const int lane = tid & 63;
    const int w    = tid >> 6;        // wave 0..15
    const int l15  = lane & 15;
    const int l4   = lane >> 4;       // 0..3
    const int row0 = blockIdx.x * BC; // first batch row of this WG

    // ---- init LDS: m <- m0, x-region <- x[:,0,:] ----
    for (int i = tid; i < BC * MDIM; i += 1024) {
        int r = i >> 9, c = i & (MDIM - 1);
        A[r][IDIM + c] = (__bf16)m0[(row0 + r) * MDIM + c];
    }
    for (int i = tid; i < BC * IDIM; i += 1024) {
        int r = i >> 7, c = i & (IDIM - 1);
        A[r][c] = (__bf16)x[(size_t)(row0 + r) * TLEN * IDIM + c];
    }
    __syncthreads();

    // per-lane constant biases: wave w owns output cols [32w, 32w+32), frags n=0,1
    const int c0 = 32 * w + l15;       // frag 0 column
    const int c1 = c0 + 16;            // frag 1 column
    const float b1r0 = b1[c0],  b1r1 = b1[c1];
    const float b2r0 = b23[c0], b2r1 = b23[c1];

    const __bf16* __restrict__ W1r0 = W1 + (size_t)c0 * K1;
    const __bf16* __restrict__ W1r1 = W1 + (size_t)c1 * K1;
    const __bf16* __restrict__ W2r0 = W23 + (size_t)c0 * K2;
    const __bf16* __restrict__ W2r1 = W23 + (size_t)c1 * K2;
    const int koff = 8 * l4;

    for (int t = 0; t < TLEN; ++t) {
        // prefetch x_{t+1} into regs (hides under G1/G23 compute)
        float2 xpre = {0.f, 0.f};
        int xr = (tid * 2) >> 7, xc = (tid * 2) & (IDIM - 1);
        if (t + 1 < TLEN) {
            xpre = *(const float2*)&x[((size_t)(row0 + xr) * TLEN + (t + 1)) * IDIM + xc];
        }

        // ---- G1: f_pre = [x|m] @ W1^T  (16 x 512, K=640) ----
        f32x4 acc0 = {0.f, 0.f, 0.f, 0.f}, acc1 = {0.f, 0.f, 0.f, 0.f};
        #pragma unroll 4
        for (int k = 0; k < K1; k += 32) {
            bf16x8 af = *(const bf16x8*)&A[l15][k + koff];
            bf16x8 bb0 = *(const bf16x8*)&W1r0[k + koff];
            bf16x8 bb1 = *(const bf16x8*)&W1r1[k + koff];
            acc0 = mfma16(af, bb0, acc0);
            acc1 = mfma16(af, bb1, acc1);
        }
        // epilogue: tanh, write f (cols 640:1152). Distinct LDS region from
        // G1 reads (0:640) -> no barrier needed before writing.
        #pragma unroll 4
        for (int r = 0; r < 4; ++r) {
            A[4 * l4 + r][IDIM + MDIM + c0] = (__bf16)tanhf(acc0[r] + b1r0);
            A[4 * l4 + r][IDIM + MDIM + c1] = (__bf16)tanhf(acc1[r] + b1r1);
        }
        __syncthreads();   // f visible to all waves

        // ---- G23: m' = [m|f] @ W23^T  (16 x 512, K=1024) ----
        f32x4 mac0 = {0.f, 0.f, 0.f, 0.f}, mac1 = {0.f, 0.f, 0.f, 0.f};
        #pragma unroll 4
        for (int k = 0; k < K2; k += 32) {
            bf16x8 af = *(const bf16x8*)&A[l15][IDIM + k + koff];
            bf16x8 bb0 = *(const bf16x8*)&W2r0[k + koff];
            bf16x8 bb1 = *(const bf16x8*)&W2r1[k + koff];
            mac0 = mfma16(af, bb0, mac0);
            mac1 = mfma16(af, bb1, mac1);
        }
        __syncthreads();   // everyone done reading m and x

        // write m' (cols 128:640) and stage x_{t+1} (cols 0:128)
        #pragma unroll 4
        for (int r = 0; r < 4; ++r) {
            A[4 * l4 + r][IDIM + c0] = (__bf16)(mac0[r] + b2r0);
            A[4 * l4 + r][IDIM + c1] = (__bf16)(mac1[r] + b2r1);
        }
        if (t + 1 < TLEN) {
            A[xr][xc]     = (__bf16)xpre.x;
            A[xr][xc + 1] = (__bf16)xpre.y;
        }
        __syncthreads();   // m,x ready for next step
    }

    // ---- output: out = m_T @ Wout^T + bout  (16 x 128), waves 0..7 ----
    if (w < 8) {
        const int oc = 16 * w + l15;
        const __bf16* __restrict__ Wor = Wo + (size_t)oc * MDIM;
        f32x4 acc = {0.f, 0.f, 0.f, 0.f};
        #pragma unroll 4
        for (int k = 0; k < MDIM; k += 32) {
            bf16x8 af = *(const bf16x8*)&A[l15][IDIM + k + koff];
            bf16x8 bb = *(const bf16x8*)&Wor[k + koff];
            acc = mfma16(af, bb, acc);
        }
        const float bb = bout[oc];
        #pragma unroll 4
        for (int r = 0; r < 4; ++r)
            out[(size_t)(row0 + 4 * l4 + r) * ODIM + oc] = acc[r] + bb;
    }
}

extern "C" void kernel_launch(void* const* d_in, const int* in_sizes, int n_in,
                              void* d_out, int out_size, void* d_ws, size_t ws_size,
                              hipStream_t stream)
{
    const float* x    = (const float*)d_in[0];
    const float* m0   = (const float*)d_in[1];
    const float* Wi2f = (const float*)d_in[2];
    const float* bi2f = (const float*)d_in[3];
    const float* Wm2f = (const float*)d_in[4];
    const float* bm2f = (const float*)d_in[5];
    const float* Wf2m = (const float*)d_in[6];
    const float* bf2m = (const float*)d_in[7];
    const float* Wm2m = (const float*)d_in[8];
    const float* bm2m = (const float*)d_in[9];
    const float* Wout = (const float*)d_in[10];
    const float* bout = (const float*)d_in[11];

    char* ws = (char*)d_ws;
    __bf16* W1  = (__bf16*)(ws + WS_W1);
    __bf16* W23 = (__bf16*)(ws + WS_W23);
    __bf16* Wo  = (__bf16*)(ws + WS_WO);
    float*  b1  = (float*)(ws + WS_B1);
    float*  b23 = (float*)(ws + WS_B23);

    const int prep_total = N_W1 + N_W23 + N_WO + FDIM + MDIM;
    lmn_prep<<<(prep_total + 255) / 256, 256, 0, stream>>>(
        Wi2f, Wm2f, Wf2m, Wm2m, Wout, bi2f, bm2f, bf2m, bm2m,
        W1, W23, Wo, b1, b23);

    lmn_scan<<<NWG, 1024, 0, stream>>>(
        x, m0, W1, W23, Wo, b1, b23, bout, (float*)d_out);
}

// Round 2
// 12378.976 us; speedup vs baseline: 1.9202x; 1.9202x over previous
//
#include <hip/hip_runtime.h>
#include <hip/hip_bf16.h>

typedef __bf16 bf16x8 __attribute__((ext_vector_type(8)));
typedef __bf16 bf16x4 __attribute__((ext_vector_type(4)));
typedef float  f32x4  __attribute__((ext_vector_type(4)));
typedef unsigned int u32;

static __device__ __forceinline__ f32x4 mfma16(bf16x8 a, bf16x8 b, f32x4 c) {
    return __builtin_amdgcn_mfma_f32_16x16x32_bf16(a, b, c, 0, 0, 0);
}

#define TLEN 512
#define IDIM 128
#define FDIM 512
#define MDIM 512
#define ODIM 128
#define BC   16      // batch rows per group
#define NGRP 16      // batch groups
#define NCU  4       // WGs (CUs) per group; CU p owns 128 F-cols + 128 M-cols
#define PSTR 520     // padded LDS stride for m/f tiles (bf16 elems; +16B keeps b128 align)
#define XSTR 136     // padded LDS stride for x tiles

// ---- workspace byte offsets ----
#define WS_WI   0                                   // Wi2f  bf16 [F][I]
#define WS_W2F  (WS_WI  + FDIM*IDIM*2)              // Wm2f  bf16 [F][M]
#define WS_W2M  (WS_W2F + FDIM*MDIM*2)              // Wm2m  bf16 [M][M]
#define WS_WF2  (WS_W2M + MDIM*MDIM*2)              // Wf2m  bf16 [M][F]
#define WS_WO   (WS_WF2 + MDIM*FDIM*2)              // Wout  bf16 [O][M]
#define WS_B1   (WS_WO  + ODIM*MDIM*2)              // bi2f+bm2f (f32)
#define WS_B23  (WS_B1  + FDIM*4)                   // bf2m+bm2m (f32)
#define WS_CTR  (WS_B23 + MDIM*4)                   // 16 barrier counters, 256B apart
#define WS_FBUF (WS_CTR + NGRP*64*4)                // f exchange: [grp][16][512] bf16
#define WS_MBUF (WS_FBUF + NGRP*BC*FDIM*2)          // m exchange: [grp][16][512] bf16

#define N_WI  (FDIM*IDIM)
#define N_W2F (FDIM*MDIM)
#define N_W2M (MDIM*MDIM)
#define N_WF2 (MDIM*FDIM)
#define N_WO  (ODIM*MDIM)

// ---------------------------------------------------------------------------
// Prep: bf16-pack the 5 weight matrices (straight casts), fuse biases, zero
// the group barrier counters. Runs every launch (graph replay resets state).
// ---------------------------------------------------------------------------
__global__ __launch_bounds__(256) void lmn_prep(
    const float* __restrict__ Wi2f, const float* __restrict__ Wm2f,
    const float* __restrict__ Wm2m, const float* __restrict__ Wf2m,
    const float* __restrict__ Wout,
    const float* __restrict__ bi2f, const float* __restrict__ bm2f,
    const float* __restrict__ bf2m, const float* __restrict__ bm2m,
    __bf16* __restrict__ WI, __bf16* __restrict__ W2F, __bf16* __restrict__ W2M,
    __bf16* __restrict__ WF2, __bf16* __restrict__ WO,
    float* __restrict__ b1, float* __restrict__ b23, u32* __restrict__ ctrs)
{
    int i = blockIdx.x * 256 + threadIdx.x;
    if (i < N_WI)  { WI[i]  = (__bf16)Wi2f[i]; return; }  i -= N_WI;
    if (i < N_W2F) { W2F[i] = (__bf16)Wm2f[i]; return; }  i -= N_W2F;
    if (i < N_W2M) { W2M[i] = (__bf16)Wm2m[i]; return; }  i -= N_W2M;
    if (i < N_WF2) { WF2[i] = (__bf16)Wf2m[i]; return; }  i -= N_WF2;
    if (i < N_WO)  { WO[i]  = (__bf16)Wout[i]; return; }  i -= N_WO;
    if (i < FDIM)  { b1[i]  = bi2f[i] + bm2f[i]; return; } i -= FDIM;
    if (i < MDIM)  { b23[i] = bf2m[i] + bm2m[i]; return; } i -= MDIM;
    if (i < NGRP * 64) { ctrs[i] = 0u; return; }
}

// ---------------------------------------------------------------------------
// Scan: 64 WGs x 512 threads (8 waves, 2/SIMD). Group g = 4 WGs, batch rows
// 16g..16g+15. WG p in group owns F-cols and M-cols [128p, 128p+128).
// Weights Wm2f/Wm2m/Wf2m slices live in registers (192 VGPR/lane) for all
// 512 steps. Per step: fused G1(m@Wm2f + x@Wi2f) + G2(m@Wm2m) -> f slice ->
// group barrier A -> gather f -> G3(f@Wf2m) -> m' slice -> barrier B ->
// gather m'. Exchange via L2-resident global buffers + monotonic atomic ctr.
// ---------------------------------------------------------------------------
__global__ __launch_bounds__(512, 2) void lmn_scan(
    const float* __restrict__ x, const float* __restrict__ m0,
    const __bf16* __restrict__ WI, const __bf16* __restrict__ W2F,
    const __bf16* __restrict__ W2M, const __bf16* __restrict__ WF2,
    const __bf16* __restrict__ WO,
    const float* __restrict__ b1, const float* __restrict__ b23,
    const float* __restrict__ bout,
    u32* __restrict__ ctrs, __bf16* __restrict__ fbuf_all,
    __bf16* __restrict__ mbuf_all, float* __restrict__ out)
{
    __shared__ __bf16 mlds[BC][PSTR];
    __shared__ __bf16 flds[BC][PSTR];
    __shared__ __bf16 xlds[2][BC][XSTR];

    const int tid  = threadIdx.x;
    const int lane = tid & 63;
    const int w    = tid >> 6;      // wave 0..7
    const int l15  = lane & 15;
    const int l4   = lane >> 4;     // 0..3
    const int koff = 8 * l4;

    const int b = blockIdx.x;
    const int g = (b & 7) * 2 + (b >> 5);   // group id (same-XCD heuristic)
    const int p = (b >> 3) & 3;             // position in group
    const int row0 = g * BC;

    u32*    ctr  = ctrs + g * 64;
    __bf16* fbuf = fbuf_all + (size_t)g * BC * FDIM;
    __bf16* mbuf = mbuf_all + (size_t)g * BC * MDIM;

    const int c0 = 128 * p + 16 * w + l15;  // this lane's output column (F and M)

    // ---- load resident weight fragments (192 VGPR/lane) ----
    bf16x8 w2f[16], w2m[16], wf2[16];
    {
        const __bf16* r2f = W2F + (size_t)c0 * MDIM;
        const __bf16* r2m = W2M + (size_t)c0 * MDIM;
        const __bf16* rf2 = WF2 + (size_t)c0 * FDIM;
        #pragma unroll
        for (int kk = 0; kk < 16; ++kk) {
            w2f[kk] = *(const bf16x8*)&r2f[kk * 32 + koff];
            w2m[kk] = *(const bf16x8*)&r2m[kk * 32 + koff];
            wf2[kk] = *(const bf16x8*)&rf2[kk * 32 + koff];
        }
    }
    const __bf16* rwi = WI + (size_t)c0 * IDIM;   // Wi2f row, streamed per step
    const float b1r = b1[c0], b2r = b23[c0];

    // ---- init LDS: m <- m0 (full 16x512), x[0] ----
    for (int u = tid; u < BC * MDIM / 4; u += 512) {
        int r = u >> 7, c = (u & 127) * 4;
        float4 v = *(const float4*)&m0[(size_t)(row0 + r) * MDIM + c];
        bf16x4 o = {(__bf16)v.x, (__bf16)v.y, (__bf16)v.z, (__bf16)v.w};
        *(bf16x4*)&mlds[r][c] = o;
    }
    {
        int r = tid >> 5, c = (tid & 31) * 4;
        float4 v = *(const float4*)&x[(size_t)(row0 + r) * TLEN * IDIM + c];
        bf16x4 o = {(__bf16)v.x, (__bf16)v.y, (__bf16)v.z, (__bf16)v.w};
        *(bf16x4*)&xlds[0][r][c] = o;
    }
    __syncthreads();

    for (int t = 0; t < TLEN; ++t) {
        // ---- fused G1 (f pre-act) + G2 (m@Wm2m) over shared m-fragments ----
        f32x4 fe = {0.f,0.f,0.f,0.f}, fo = {0.f,0.f,0.f,0.f};
        f32x4 me = {0.f,0.f,0.f,0.f}, mo = {0.f,0.f,0.f,0.f};
        const __bf16 (*xcur)[XSTR] = xlds[t & 1];
        #pragma unroll
        for (int j = 0; j < 4; ++j) {
            bf16x8 ax = *(const bf16x8*)&xcur[l15][j * 32 + koff];
            bf16x8 bw = *(const bf16x8*)&rwi[j * 32 + koff];
            if (j & 1) fo = mfma16(ax, bw, fo); else fe = mfma16(ax, bw, fe);
        }
        #pragma unroll
        for (int kk = 0; kk < 16; ++kk) {
            bf16x8 am = *(const bf16x8*)&mlds[l15][kk * 32 + koff];
            if (kk & 1) { fo = mfma16(am, w2f[kk], fo); mo = mfma16(am, w2m[kk], mo); }
            else        { fe = mfma16(am, w2f[kk], fe); me = mfma16(am, w2m[kk], me); }
        }
        f32x4 facc = fe + fo;
        #pragma unroll
        for (int r = 0; r < 4; ++r) {
            __bf16 fb = (__bf16)tanhf(facc[r] + b1r);
            flds[4 * l4 + r][c0] = fb;
            fbuf[(4 * l4 + r) * FDIM + c0] = fb;
        }
        __syncthreads();                       // all waves' f stores drained
        if (tid == 0) {
            __threadfence();
            __hip_atomic_fetch_add(ctr, 1u, __ATOMIC_RELEASE, __HIP_MEMORY_SCOPE_AGENT);
        }
        // overlap the barrier-A wait: stage x_{t+1}
        if (t + 1 < TLEN) {
            int r = tid >> 5, c = (tid & 31) * 4;
            float4 v = *(const float4*)&x[((size_t)(row0 + r) * TLEN + (t + 1)) * IDIM + c];
            bf16x4 o = {(__bf16)v.x, (__bf16)v.y, (__bf16)v.z, (__bf16)v.w};
            *(bf16x4*)&xlds[(t + 1) & 1][r][c] = o;
        }
        if (tid == 0) {                        // wait A
            u32 tgt = 4u * (2u * t + 1u);
            while (__hip_atomic_load(ctr, __ATOMIC_ACQUIRE, __HIP_MEMORY_SCOPE_AGENT) < tgt)
                __builtin_amdgcn_s_sleep(2);
        }
        __syncthreads();
        __threadfence();                       // invalidate L1 before peer reads
        #pragma unroll
        for (int j = 1; j < 4; ++j) {          // gather peers' f slices
            int q = (p + j) & 3;
            int r = tid >> 5, cc = 128 * q + (tid & 31) * 4;
            bf16x4 v = *(const bf16x4*)&fbuf[r * FDIM + cc];
            *(bf16x4*)&flds[r][cc] = v;
        }
        __syncthreads();

        // ---- G3: m' += f @ Wf2m ----
        #pragma unroll
        for (int kk = 0; kk < 16; ++kk) {
            bf16x8 af = *(const bf16x8*)&flds[l15][kk * 32 + koff];
            if (kk & 1) mo = mfma16(af, wf2[kk], mo); else me = mfma16(af, wf2[kk], me);
        }
        f32x4 macc = me + mo;
        #pragma unroll
        for (int r = 0; r < 4; ++r) {
            __bf16 mb = (__bf16)(macc[r] + b2r);
            mlds[4 * l4 + r][c0] = mb;         // own slice (local reads all done)
            mbuf[(4 * l4 + r) * MDIM + c0] = mb;
        }
        __syncthreads();                       // drain m' stores
        if (tid == 0) {
            __threadfence();
            __hip_atomic_fetch_add(ctr, 1u, __ATOMIC_RELEASE, __HIP_MEMORY_SCOPE_AGENT);
            u32 tgt = 4u * (2u * t + 2u);      // wait B
            while (__hip_atomic_load(ctr, __ATOMIC_ACQUIRE, __HIP_MEMORY_SCOPE_AGENT) < tgt)
                __builtin_amdgcn_s_sleep(2);
        }
        __syncthreads();
        __threadfence();
        #pragma unroll
        for (int j = 1; j < 4; ++j) {          // gather peers' m' slices
            int q = (p + j) & 3;
            int r = tid >> 5, cc = 128 * q + (tid & 31) * 4;
            bf16x4 v = *(const bf16x4*)&mbuf[r * MDIM + cc];
            *(bf16x4*)&mlds[r][cc] = v;
        }
        __syncthreads();
    }

    // ---- epilogue: out cols [32p, 32p+32), waves 0..1 ----
    if (w < 2) {
        const int oc = 32 * p + 16 * w + l15;
        const __bf16* ro = WO + (size_t)oc * MDIM;
        f32x4 oe = {0.f,0.f,0.f,0.f}, oo = {0.f,0.f,0.f,0.f};
        #pragma unroll
        for (int kk = 0; kk < 16; ++kk) {
            bf16x8 am = *(const bf16x8*)&mlds[l15][kk * 32 + koff];
            bf16x8 bw = *(const bf16x8*)&ro[kk * 32 + koff];
            if (kk & 1) oo = mfma16(am, bw, oo); else oe = mfma16(am, bw, oe);
        }
        f32x4 oacc = oe + oo;
        const float bo = bout[oc];
        #pragma unroll
        for (int r = 0; r < 4; ++r)
            out[(size_t)(row0 + 4 * l4 + r) * ODIM + oc] = oacc[r] + bo;
    }
}

extern "C" void kernel_launch(void* const* d_in, const int* in_sizes, int n_in,
                              void* d_out, int out_size, void* d_ws, size_t ws_size,
                              hipStream_t stream)
{
    const float* x    = (const float*)d_in[0];
    const float* m0   = (const float*)d_in[1];
    const float* Wi2f = (const float*)d_in[2];
    const float* bi2f = (const float*)d_in[3];
    const float* Wm2f = (const float*)d_in[4];
    const float* bm2f = (const float*)d_in[5];
    const float* Wf2m = (const float*)d_in[6];
    const float* bf2m = (const float*)d_in[7];
    const float* Wm2m = (const float*)d_in[8];
    const float* bm2m = (const float*)d_in[9];
    const float* Wout = (const float*)d_in[10];
    const float* bout = (const float*)d_in[11];

    char* ws = (char*)d_ws;
    __bf16* WI  = (__bf16*)(ws + WS_WI);
    __bf16* W2F = (__bf16*)(ws + WS_W2F);
    __bf16* W2M = (__bf16*)(ws + WS_W2M);
    __bf16* WF2 = (__bf16*)(ws + WS_WF2);
    __bf16* WO  = (__bf16*)(ws + WS_WO);
    float*  b1  = (float*)(ws + WS_B1);
    float*  b23 = (float*)(ws + WS_B23);
    u32*    ctr = (u32*)(ws + WS_CTR);
    __bf16* fb  = (__bf16*)(ws + WS_FBUF);
    __bf16* mb  = (__bf16*)(ws + WS_MBUF);

    const int prep_total = N_WI + N_W2F + N_W2M + N_WF2 + N_WO + FDIM + MDIM + NGRP * 64;
    lmn_prep<<<(prep_total + 255) / 256, 256, 0, stream>>>(
        Wi2f, Wm2f, Wm2m, Wf2m, Wout, bi2f, bm2f, bf2m, bm2m,
        WI, W2F, W2M, WF2, WO, b1, b23, ctr);

    lmn_scan<<<NCU * NGRP, 512, 0, stream>>>(
        x, m0, WI, W2F, W2M, WF2, WO, b1, b23, bout, ctr, fb, mb, (float*)d_out);
}

// Round 3
// 5992.211 us; speedup vs baseline: 3.9669x; 2.0658x over previous
//
#include <hip/hip_runtime.h>
#include <hip/hip_bf16.h>

typedef __bf16 bf16x8 __attribute__((ext_vector_type(8)));
typedef __bf16 bf16x4 __attribute__((ext_vector_type(4)));
typedef float  f32x4  __attribute__((ext_vector_type(4)));
typedef unsigned int u32;
typedef unsigned long long u64;

static __device__ __forceinline__ f32x4 mfma16(bf16x8 a, bf16x8 b, f32x4 c) {
    return __builtin_amdgcn_mfma_f32_16x16x32_bf16(a, b, c, 0, 0, 0);
}
static __device__ __forceinline__ f32x4 mfma16v(bf16x8 a, f32x4 bw, f32x4 c) {
    return mfma16(a, __builtin_bit_cast(bf16x8, bw), c);
}

#define TLEN 512
#define IDIM 128
#define FDIM 512
#define MDIM 512
#define ODIM 128
#define BC   16      // batch rows per group
#define NGRP 16      // batch groups
#define NCU  4       // WGs (CUs) per group; CU p owns 128 F-cols + 128 M-cols
#define PSTR 520     // padded LDS stride for m/f tiles (bf16 elems)
#define XSTR 136     // padded LDS stride for x tiles

// ---- workspace byte offsets ----
#define WS_WI   0
#define WS_W2F  (WS_WI  + FDIM*IDIM*2)
#define WS_W2M  (WS_W2F + FDIM*MDIM*2)
#define WS_WF2  (WS_W2M + MDIM*MDIM*2)
#define WS_WO   (WS_WF2 + MDIM*FDIM*2)
#define WS_B1   (WS_WO  + ODIM*MDIM*2)
#define WS_B23  (WS_B1  + FDIM*4)
#define WS_CTR  (WS_B23 + MDIM*4)
#define WS_FBUF (WS_CTR + NGRP*64*4)
#define WS_MBUF (WS_FBUF + NGRP*BC*FDIM*2)

#define N_WI  (FDIM*IDIM)
#define N_W2F (FDIM*MDIM)
#define N_W2M (MDIM*MDIM)
#define N_WF2 (MDIM*FDIM)
#define N_WO  (ODIM*MDIM)

__global__ __launch_bounds__(256) void lmn_prep(
    const float* __restrict__ Wi2f, const float* __restrict__ Wm2f,
    const float* __restrict__ Wm2m, const float* __restrict__ Wf2m,
    const float* __restrict__ Wout,
    const float* __restrict__ bi2f, const float* __restrict__ bm2f,
    const float* __restrict__ bf2m, const float* __restrict__ bm2m,
    __bf16* __restrict__ WI, __bf16* __restrict__ W2F, __bf16* __restrict__ W2M,
    __bf16* __restrict__ WF2, __bf16* __restrict__ WO,
    float* __restrict__ b1, float* __restrict__ b23, u32* __restrict__ ctrs)
{
    int i = blockIdx.x * 256 + threadIdx.x;
    if (i < N_WI)  { WI[i]  = (__bf16)Wi2f[i]; return; }  i -= N_WI;
    if (i < N_W2F) { W2F[i] = (__bf16)Wm2f[i]; return; }  i -= N_W2F;
    if (i < N_W2M) { W2M[i] = (__bf16)Wm2m[i]; return; }  i -= N_W2M;
    if (i < N_WF2) { WF2[i] = (__bf16)Wf2m[i]; return; }  i -= N_WF2;
    if (i < N_WO)  { WO[i]  = (__bf16)Wout[i]; return; }  i -= N_WO;
    if (i < FDIM)  { b1[i]  = bi2f[i] + bm2f[i]; return; } i -= FDIM;
    if (i < MDIM)  { b23[i] = bf2m[i] + bm2m[i]; return; } i -= MDIM;
    if (i < NGRP * 64) { ctrs[i] = 0u; return; }
}

// ---------------------------------------------------------------------------
// Scan: 64 WGs x 512 threads. Group g = 4 WGs (same-XCD heuristic), batch
// rows 16g..16g+15. WG p owns F/M cols [128p,128p+128). All weight slices
// pinned in VGPRs via asm anti-remat. Cross-CU exchange is fence-free:
// relaxed agent-scope 8B atomics (coherent, no L2 flush) + per-wave
// s_waitcnt vmcnt(0) + relaxed counter arrival, all-thread relaxed spin.
// ---------------------------------------------------------------------------
__global__ __launch_bounds__(512, 2) void lmn_scan(
    const float* __restrict__ x, const float* __restrict__ m0,
    const __bf16* __restrict__ WI, const __bf16* __restrict__ W2F,
    const __bf16* __restrict__ W2M, const __bf16* __restrict__ WF2,
    const __bf16* __restrict__ WO,
    const float* __restrict__ b1, const float* __restrict__ b23,
    const float* __restrict__ bout,
    u32* __restrict__ ctrs, __bf16* __restrict__ fbuf_all,
    __bf16* __restrict__ mbuf_all, float* __restrict__ out)
{
    __shared__ __bf16 mlds[BC][PSTR];
    __shared__ __bf16 flds[BC][PSTR];
    __shared__ __bf16 xlds[2][BC][XSTR];

    const int tid  = threadIdx.x;
    const int lane = tid & 63;
    const int w    = tid >> 6;
    const int l15  = lane & 15;
    const int l4   = lane >> 4;
    const int koff = 8 * l4;

    const int b = blockIdx.x;
    const int g = (b & 7) * 2 + (b >> 5);   // group id (members share XCD)
    const int p = (b >> 3) & 3;             // position in group
    const int row0 = g * BC;

    u32*    ctr  = ctrs + g * 64;
    __bf16* fbuf = fbuf_all + (size_t)g * BC * FDIM;
    __bf16* mbuf = mbuf_all + (size_t)g * BC * MDIM;

    const int c0 = 128 * p + 16 * w + l15;  // lane's output column (F and M)

    // ---- resident weight fragments, pinned (52 x f32x4 = 208 VGPR) ----
    f32x4 w2f[16], w2m[16], wf2[16], wi[4];
    {
        const __bf16* r2f = W2F + (size_t)c0 * MDIM;
        const __bf16* r2m = W2M + (size_t)c0 * MDIM;
        const __bf16* rf2 = WF2 + (size_t)c0 * FDIM;
        const __bf16* rwi = WI  + (size_t)c0 * IDIM;
        #pragma unroll
        for (int j = 0; j < 16; ++j) {
            w2f[j] = *(const f32x4*)&r2f[j * 32 + koff];
            w2m[j] = *(const f32x4*)&r2m[j * 32 + koff];
            wf2[j] = *(const f32x4*)&rf2[(((4 * p + j) & 15)) * 32 + koff]; // rotated
        }
        #pragma unroll
        for (int j = 0; j < 4; ++j) wi[j] = *(const f32x4*)&rwi[j * 32 + koff];
        #pragma unroll
        for (int j = 0; j < 16; ++j)
            asm volatile("" : "+v"(w2f[j]), "+v"(w2m[j]), "+v"(wf2[j]));
        #pragma unroll
        for (int j = 0; j < 4; ++j) asm volatile("" : "+v"(wi[j]));
    }
    const float b1r = b1[c0], b2r = b23[c0];

    // ---- init LDS: m <- m0, x[0] ----
    for (int u = tid; u < BC * MDIM / 4; u += 512) {
        int r = u >> 7, c = (u & 127) * 4;
        float4 v = *(const float4*)&m0[(size_t)(row0 + r) * MDIM + c];
        bf16x4 o = {(__bf16)v.x, (__bf16)v.y, (__bf16)v.z, (__bf16)v.w};
        *(bf16x4*)&mlds[r][c] = o;
    }
    {
        int r = tid >> 5, c = (tid & 31) * 4;
        float4 v = *(const float4*)&x[(size_t)(row0 + r) * TLEN * IDIM + c];
        bf16x4 o = {(__bf16)v.x, (__bf16)v.y, (__bf16)v.z, (__bf16)v.w};
        *(bf16x4*)&xlds[0][r][c] = o;
    }

    const int xr = tid >> 5, xc = (tid & 31) * 4;          // x/exchange tiling
    const int ec = (tid & 31) * 4;                          // export col within block

    for (int t = 0; t < TLEN; ++t) {
        __syncthreads();   // mlds/xlds fully ready (init or prev gather)

        // early HBM issue: x_{t+1}
        float4 xpre = {0.f, 0.f, 0.f, 0.f};
        if (t + 1 < TLEN)
            xpre = *(const float4*)&x[((size_t)(row0 + xr) * TLEN + (t + 1)) * IDIM + xc];

        // ---- G1 (x-part + m-part) and G2, weights in regs ----
        f32x4 fe = {0,0,0,0}, fo = {0,0,0,0}, me = {0,0,0,0}, mo = {0,0,0,0};
        const __bf16 (*xcur)[XSTR] = xlds[t & 1];
        #pragma unroll
        for (int j = 0; j < 4; ++j) {
            bf16x8 ax = *(const bf16x8*)&xcur[l15][j * 32 + koff];
            if (j & 1) fo = mfma16v(ax, wi[j], fo); else fe = mfma16v(ax, wi[j], fe);
        }
        #pragma unroll
        for (int kk = 0; kk < 16; ++kk) {
            bf16x8 am = *(const bf16x8*)&mlds[l15][kk * 32 + koff];
            if (kk & 1) { fo = mfma16v(am, w2f[kk], fo); mo = mfma16v(am, w2m[kk], mo); }
            else        { fe = mfma16v(am, w2f[kk], fe); me = mfma16v(am, w2m[kk], me); }
        }
        f32x4 facc = fe + fo;
        #pragma unroll
        for (int r = 0; r < 4; ++r)
            flds[4 * l4 + r][c0] = (__bf16)tanhf(facc[r] + b1r);
        __syncthreads();   // S1: own f slice in LDS, all mlds reads done

        // export own f block; overlap G3 partial over own f cols
        {
            u64 v = *(const u64*)&flds[xr][128 * p + ec];
            __hip_atomic_store((u64*)&fbuf[xr * FDIM + 128 * p + ec], v,
                               __ATOMIC_RELAXED, __HIP_MEMORY_SCOPE_AGENT);
        }
        #pragma unroll
        for (int j = 0; j < 4; ++j) {          // wf2[j] holds phys kk=4p+j
            int kk = (4 * p + j) & 15;
            bf16x8 af = *(const bf16x8*)&flds[l15][kk * 32 + koff];
            if (j & 1) mo = mfma16v(af, wf2[j], mo); else me = mfma16v(af, wf2[j], me);
        }
        asm volatile("s_waitcnt vmcnt(0)" ::: "memory");
        if (lane == 0)
            __hip_atomic_fetch_add(ctr, 1u, __ATOMIC_RELAXED, __HIP_MEMORY_SCOPE_AGENT);
        {
            u32 tgt = 32u * (2u * (u32)t + 1u);
            while (__hip_atomic_load(ctr, __ATOMIC_RELAXED, __HIP_MEMORY_SCOPE_AGENT) < tgt) {}
        }
        asm volatile("" ::: "memory");
        #pragma unroll
        for (int j = 1; j < 4; ++j) {          // gather peers' f
            int q = (p + j) & 3;
            u64 v = __hip_atomic_load((const u64*)&fbuf[xr * FDIM + 128 * q + ec],
                                      __ATOMIC_RELAXED, __HIP_MEMORY_SCOPE_AGENT);
            *(u64*)&flds[xr][128 * q + ec] = v;
        }
        __syncthreads();   // S3: flds full

        // ---- G3 remaining 12 k-slices ----
        #pragma unroll
        for (int j = 4; j < 16; ++j) {
            int kk = (4 * p + j) & 15;
            bf16x8 af = *(const bf16x8*)&flds[l15][kk * 32 + koff];
            if (j & 1) mo = mfma16v(af, wf2[j], mo); else me = mfma16v(af, wf2[j], me);
        }
        f32x4 macc = me + mo;
        #pragma unroll
        for (int r = 0; r < 4; ++r)
            mlds[4 * l4 + r][c0] = (__bf16)(macc[r] + b2r);
        if (t + 1 < TLEN) {
            bf16x4 o = {(__bf16)xpre.x, (__bf16)xpre.y, (__bf16)xpre.z, (__bf16)xpre.w};
            *(bf16x4*)&xlds[(t + 1) & 1][xr][xc] = o;
        }
        __syncthreads();   // S4: own m' slice in LDS

        // export own m' block
        {
            u64 v = *(const u64*)&mlds[xr][128 * p + ec];
            __hip_atomic_store((u64*)&mbuf[xr * MDIM + 128 * p + ec], v,
                               __ATOMIC_RELAXED, __HIP_MEMORY_SCOPE_AGENT);
        }
        asm volatile("s_waitcnt vmcnt(0)" ::: "memory");
        if (lane == 0)
            __hip_atomic_fetch_add(ctr, 1u, __ATOMIC_RELAXED, __HIP_MEMORY_SCOPE_AGENT);
        {
            u32 tgt = 32u * (2u * (u32)t + 2u);
            while (__hip_atomic_load(ctr, __ATOMIC_RELAXED, __HIP_MEMORY_SCOPE_AGENT) < tgt) {}
        }
        asm volatile("" ::: "memory");
        #pragma unroll
        for (int j = 1; j < 4; ++j) {          // gather peers' m'
            int q = (p + j) & 3;
            u64 v = __hip_atomic_load((const u64*)&mbuf[xr * MDIM + 128 * q + ec],
                                      __ATOMIC_RELAXED, __HIP_MEMORY_SCOPE_AGENT);
            *(u64*)&mlds[xr][128 * q + ec] = v;
        }
    }
    __syncthreads();

    // ---- epilogue: out cols [32p, 32p+32), waves 0..1 ----
    if (w < 2) {
        const int oc = 32 * p + 16 * w + l15;
        const __bf16* ro = WO + (size_t)oc * MDIM;
        f32x4 oe = {0,0,0,0}, oo = {0,0,0,0};
        #pragma unroll
        for (int kk = 0; kk < 16; ++kk) {
            bf16x8 am = *(const bf16x8*)&mlds[l15][kk * 32 + koff];
            bf16x8 bw = *(const bf16x8*)&ro[kk * 32 + koff];
            if (kk & 1) oo = mfma16(am, bw, oo); else oe = mfma16(am, bw, oe);
        }
        f32x4 oacc = oe + oo;
        const float bo = bout[oc];
        #pragma unroll
        for (int r = 0; r < 4; ++r)
            out[(size_t)(row0 + 4 * l4 + r) * ODIM + oc] = oacc[r] + bo;
    }
}

extern "C" void kernel_launch(void* const* d_in, const int* in_sizes, int n_in,
                              void* d_out, int out_size, void* d_ws, size_t ws_size,
                              hipStream_t stream)
{
    const float* x    = (const float*)d_in[0];
    const float* m0   = (const float*)d_in[1];
    const float* Wi2f = (const float*)d_in[2];
    const float* bi2f = (const float*)d_in[3];
    const float* Wm2f = (const float*)d_in[4];
    const float* bm2f = (const float*)d_in[5];
    const float* Wf2m = (const float*)d_in[6];
    const float* bf2m = (const float*)d_in[7];
    const float* Wm2m = (const float*)d_in[8];
    const float* bm2m = (const float*)d_in[9];
    const float* Wout = (const float*)d_in[10];
    const float* bout = (const float*)d_in[11];

    char* ws = (char*)d_ws;
    __bf16* WI  = (__bf16*)(ws + WS_WI);
    __bf16* W2F = (__bf16*)(ws + WS_W2F);
    __bf16* W2M = (__bf16*)(ws + WS_W2M);
    __bf16* WF2 = (__bf16*)(ws + WS_WF2);
    __bf16* WO  = (__bf16*)(ws + WS_WO);
    float*  b1  = (float*)(ws + WS_B1);
    float*  b23 = (float*)(ws + WS_B23);
    u32*    ctr = (u32*)(ws + WS_CTR);
    __bf16* fb  = (__bf16*)(ws + WS_FBUF);
    __bf16* mb  = (__bf16*)(ws + WS_MBUF);

    const int prep_total = N_WI + N_W2F + N_W2M + N_WF2 + N_WO + FDIM + MDIM + NGRP * 64;
    lmn_prep<<<(prep_total + 255) / 256, 256, 0, stream>>>(
        Wi2f, Wm2f, Wm2m, Wf2m, Wout, bi2f, bm2f, bf2m, bm2m,
        WI, W2F, W2M, WF2, WO, b1, b23, ctr);

    lmn_scan<<<NCU * NGRP, 512, 0, stream>>>(
        x, m0, WI, W2F, W2M, WF2, WO, b1, b23, bout, ctr, fb, mb, (float*)d_out);
}

// Round 4
// 3120.032 us; speedup vs baseline: 7.6186x; 1.9206x over previous
//
#include <hip/hip_runtime.h>
#include <hip/hip_bf16.h>

typedef __bf16 bf16x8 __attribute__((ext_vector_type(8)));
typedef __bf16 bf16x4 __attribute__((ext_vector_type(4)));
typedef float  f32x4  __attribute__((ext_vector_type(4)));
typedef unsigned int u32;
typedef unsigned long long u64;

static __device__ __forceinline__ f32x4 mfma16(bf16x8 a, bf16x8 b, f32x4 c) {
    return __builtin_amdgcn_mfma_f32_16x16x32_bf16(a, b, c, 0, 0, 0);
}
static __device__ __forceinline__ f32x4 mfma16v(bf16x8 a, f32x4 bw, f32x4 c) {
    return mfma16(a, __builtin_bit_cast(bf16x8, bw), c);
}

#define TLEN 512
#define IDIM 128
#define FDIM 512
#define MDIM 512
#define ODIM 128
#define BC   16      // batch rows per group
#define NGRP 16      // batch groups
#define NCU  4       // WGs (CUs) per group; CU p owns 128 F-cols + 128 M-cols
#define PSTR 520     // padded LDS stride for m/f tiles (bf16 elems)
#define XSTR 136     // padded LDS stride for x tiles

// ---- workspace byte offsets ----
#define WS_WI   0
#define WS_W2F  (WS_WI  + FDIM*IDIM*2)
#define WS_W2M  (WS_W2F + FDIM*MDIM*2)
#define WS_WF2  (WS_W2M + MDIM*MDIM*2)
#define WS_WO   (WS_WF2 + MDIM*FDIM*2)
#define WS_B1   (WS_WO  + ODIM*MDIM*2)
#define WS_B23  (WS_B1  + FDIM*4)
#define WS_CTR  (WS_B23 + MDIM*4)
#define WS_FBUF (WS_CTR + NGRP*64*4)
#define WS_MBUF (WS_FBUF + NGRP*BC*FDIM*2)

#define N_WI  (FDIM*IDIM)
#define N_W2F (FDIM*MDIM)
#define N_W2M (MDIM*MDIM)
#define N_WF2 (MDIM*FDIM)
#define N_WO  (ODIM*MDIM)

__global__ __launch_bounds__(256) void lmn_prep(
    const float* __restrict__ Wi2f, const float* __restrict__ Wm2f,
    const float* __restrict__ Wm2m, const float* __restrict__ Wf2m,
    const float* __restrict__ Wout,
    const float* __restrict__ bi2f, const float* __restrict__ bm2f,
    const float* __restrict__ bf2m, const float* __restrict__ bm2m,
    __bf16* __restrict__ WI, __bf16* __restrict__ W2F, __bf16* __restrict__ W2M,
    __bf16* __restrict__ WF2, __bf16* __restrict__ WO,
    float* __restrict__ b1, float* __restrict__ b23, u32* __restrict__ ctrs)
{
    int i = blockIdx.x * 256 + threadIdx.x;
    if (i < N_WI)  { WI[i]  = (__bf16)Wi2f[i]; return; }  i -= N_WI;
    if (i < N_W2F) { W2F[i] = (__bf16)Wm2f[i]; return; }  i -= N_W2F;
    if (i < N_W2M) { W2M[i] = (__bf16)Wm2m[i]; return; }  i -= N_W2M;
    if (i < N_WF2) { WF2[i] = (__bf16)Wf2m[i]; return; }  i -= N_WF2;
    if (i < N_WO)  { WO[i]  = (__bf16)Wout[i]; return; }  i -= N_WO;
    if (i < FDIM)  { b1[i]  = bi2f[i] + bm2f[i]; return; } i -= FDIM;
    if (i < MDIM)  { b23[i] = bf2m[i] + bm2m[i]; return; } i -= MDIM;
    if (i < NGRP * 64) { ctrs[i] = 0u; return; }
}

// ---------------------------------------------------------------------------
// Scan: 64 WGs x 512 threads. Group g = 4 WGs, batch rows 16g..16g+15.
// WG p owns F/M cols [128p,128p+128). Exchange protocol (this round's change):
//   arrive-early/wait-late, ONE relaxed agent fetch_add per WG per event,
//   ONE spinner (tid0) with s_sleep backoff, syncthreads release.
//   RTT window A hides G2 + own-block G3 slices; window B hides x staging.
// ---------------------------------------------------------------------------
__global__ __launch_bounds__(512, 2) void lmn_scan(
    const float* __restrict__ x, const float* __restrict__ m0,
    const __bf16* __restrict__ WI, const __bf16* __restrict__ W2F,
    const __bf16* __restrict__ W2M, const __bf16* __restrict__ WF2,
    const __bf16* __restrict__ WO,
    const float* __restrict__ b1, const float* __restrict__ b23,
    const float* __restrict__ bout,
    u32* __restrict__ ctrs, __bf16* __restrict__ fbuf_all,
    __bf16* __restrict__ mbuf_all, float* __restrict__ out)
{
    __shared__ __bf16 mlds[BC][PSTR];
    __shared__ __bf16 flds[BC][PSTR];
    __shared__ __bf16 xlds[2][BC][XSTR];

    const int tid  = threadIdx.x;
    const int lane = tid & 63;
    const int w    = tid >> 6;
    const int l15  = lane & 15;
    const int l4   = lane >> 4;
    const int koff = 8 * l4;

    const int b = blockIdx.x;
    const int g = (b & 7) * 2 + (b >> 5);   // group id (members share XCD)
    const int p = (b >> 3) & 3;             // position in group
    const int row0 = g * BC;

    u32*    ctr  = ctrs + g * 64;
    __bf16* fbuf = fbuf_all + (size_t)g * BC * FDIM;
    __bf16* mbuf = mbuf_all + (size_t)g * BC * MDIM;

    const int c0 = 128 * p + 16 * w + l15;  // lane's output column (F and M)

    // ---- weight fragments (compiler may keep or spill; addressed next round) ----
    f32x4 w2f[16], w2m[16], wf2[16], wi[4];
    {
        const __bf16* r2f = W2F + (size_t)c0 * MDIM;
        const __bf16* r2m = W2M + (size_t)c0 * MDIM;
        const __bf16* rf2 = WF2 + (size_t)c0 * FDIM;
        const __bf16* rwi = WI  + (size_t)c0 * IDIM;
        #pragma unroll
        for (int j = 0; j < 16; ++j) {
            w2f[j] = *(const f32x4*)&r2f[j * 32 + koff];
            w2m[j] = *(const f32x4*)&r2m[j * 32 + koff];
            wf2[j] = *(const f32x4*)&rf2[(((4 * p + j) & 15)) * 32 + koff]; // rotated
        }
        #pragma unroll
        for (int j = 0; j < 4; ++j) wi[j] = *(const f32x4*)&rwi[j * 32 + koff];
        #pragma unroll
        for (int j = 0; j < 16; ++j)
            asm volatile("" : "+v"(w2f[j]), "+v"(w2m[j]), "+v"(wf2[j]));
        #pragma unroll
        for (int j = 0; j < 4; ++j) asm volatile("" : "+v"(wi[j]));
    }
    const float b1r = b1[c0], b2r = b23[c0];

    // ---- init LDS: m <- m0, x[0] ----
    for (int u = tid; u < BC * MDIM / 4; u += 512) {
        int r = u >> 7, c = (u & 127) * 4;
        float4 v = *(const float4*)&m0[(size_t)(row0 + r) * MDIM + c];
        bf16x4 o = {(__bf16)v.x, (__bf16)v.y, (__bf16)v.z, (__bf16)v.w};
        *(bf16x4*)&mlds[r][c] = o;
    }
    {
        int r = tid >> 5, c = (tid & 31) * 4;
        float4 v = *(const float4*)&x[(size_t)(row0 + r) * TLEN * IDIM + c];
        bf16x4 o = {(__bf16)v.x, (__bf16)v.y, (__bf16)v.z, (__bf16)v.w};
        *(bf16x4*)&xlds[0][r][c] = o;
    }

    const int xr = tid >> 5, xc = (tid & 31) * 4;
    const int ec = (tid & 31) * 4;

    for (int t = 0; t < TLEN; ++t) {
        __syncthreads();   // mlds/xlds fully ready (init or prev gather)

        // early HBM issue: x_{t+1}
        float4 xpre = {0.f, 0.f, 0.f, 0.f};
        if (t + 1 < TLEN)
            xpre = *(const float4*)&x[((size_t)(row0 + xr) * TLEN + (t + 1)) * IDIM + xc];

        // ---- G1: f_pre = x@Wi2f + m@Wm2f ----
        f32x4 fe = {0,0,0,0}, fo = {0,0,0,0};
        const __bf16 (*xcur)[XSTR] = xlds[t & 1];
        #pragma unroll
        for (int j = 0; j < 4; ++j) {
            bf16x8 ax = *(const bf16x8*)&xcur[l15][j * 32 + koff];
            if (j & 1) fo = mfma16v(ax, wi[j], fo); else fe = mfma16v(ax, wi[j], fe);
        }
        #pragma unroll
        for (int kk = 0; kk < 16; ++kk) {
            bf16x8 am = *(const bf16x8*)&mlds[l15][kk * 32 + koff];
            if (kk & 1) fo = mfma16v(am, w2f[kk], fo);
            else        fe = mfma16v(am, w2f[kk], fe);
        }
        f32x4 facc = fe + fo;
        #pragma unroll
        for (int r = 0; r < 4; ++r)
            flds[4 * l4 + r][c0] = (__bf16)tanhf(facc[r] + b1r);
        __syncthreads();   // S1: own f block complete in LDS

        // export own f block (1x u64 relaxed agent store per thread)
        {
            u64 v = *(const u64*)&flds[xr][128 * p + ec];
            __hip_atomic_store((u64*)&fbuf[xr * FDIM + 128 * p + ec], v,
                               __ATOMIC_RELAXED, __HIP_MEMORY_SCOPE_AGENT);
        }
        asm volatile("s_waitcnt vmcnt(0)" ::: "memory");
        __syncthreads();   // S2: all exports drained
        if (tid == 0)      // arrive A (early)
            __hip_atomic_fetch_add(ctr, 1u, __ATOMIC_RELAXED, __HIP_MEMORY_SCOPE_AGENT);

        // ---- RTT window A: G2 (m@Wm2m) + own-block G3 slices ----
        f32x4 me = {0,0,0,0}, mo = {0,0,0,0};
        #pragma unroll
        for (int kk = 0; kk < 16; ++kk) {
            bf16x8 am = *(const bf16x8*)&mlds[l15][kk * 32 + koff];
            if (kk & 1) mo = mfma16v(am, w2m[kk], mo);
            else        me = mfma16v(am, w2m[kk], me);
        }
        #pragma unroll
        for (int j = 0; j < 4; ++j) {          // wf2[j] holds phys kk=4p+j (own block)
            int kk = (4 * p + j) & 15;
            bf16x8 af = *(const bf16x8*)&flds[l15][kk * 32 + koff];
            if (j & 1) mo = mfma16v(af, wf2[j], mo); else me = mfma16v(af, wf2[j], me);
        }

        if (tid == 0) {    // wait A (late)
            u32 tgt = 8u * (u32)t + 4u;
            while (__hip_atomic_load(ctr, __ATOMIC_RELAXED, __HIP_MEMORY_SCOPE_AGENT) < tgt)
                __builtin_amdgcn_s_sleep(1);
        }
        __syncthreads();   // S3: release
        #pragma unroll
        for (int j = 1; j < 4; ++j) {          // gather peers' f
            int q = (p + j) & 3;
            u64 v = __hip_atomic_load((const u64*)&fbuf[xr * FDIM + 128 * q + ec],
                                      __ATOMIC_RELAXED, __HIP_MEMORY_SCOPE_AGENT);
            *(u64*)&flds[xr][128 * q + ec] = v;
        }
        __syncthreads();   // S4: flds full

        // ---- G3 remaining 12 k-slices (peer blocks) ----
        #pragma unroll
        for (int j = 4; j < 16; ++j) {
            int kk = (4 * p + j) & 15;
            bf16x8 af = *(const bf16x8*)&flds[l15][kk * 32 + koff];
            if (j & 1) mo = mfma16v(af, wf2[j], mo); else me = mfma16v(af, wf2[j], me);
        }
        f32x4 macc = me + mo;
        #pragma unroll
        for (int r = 0; r < 4; ++r)
            mlds[4 * l4 + r][c0] = (__bf16)(macc[r] + b2r);
        __syncthreads();   // S5: own m' block complete in LDS

        // export own m' block
        {
            u64 v = *(const u64*)&mlds[xr][128 * p + ec];
            __hip_atomic_store((u64*)&mbuf[xr * MDIM + 128 * p + ec], v,
                               __ATOMIC_RELAXED, __HIP_MEMORY_SCOPE_AGENT);
        }
        asm volatile("s_waitcnt vmcnt(0)" ::: "memory");
        __syncthreads();   // S6: exports drained
        if (tid == 0)      // arrive B (early)
            __hip_atomic_fetch_add(ctr, 1u, __ATOMIC_RELAXED, __HIP_MEMORY_SCOPE_AGENT);

        // ---- RTT window B: stage x_{t+1} into LDS ----
        if (t + 1 < TLEN) {
            bf16x4 o = {(__bf16)xpre.x, (__bf16)xpre.y, (__bf16)xpre.z, (__bf16)xpre.w};
            *(bf16x4*)&xlds[(t + 1) & 1][xr][xc] = o;
        }

        if (tid == 0) {    // wait B (late)
            u32 tgt = 8u * (u32)t + 8u;
            while (__hip_atomic_load(ctr, __ATOMIC_RELAXED, __HIP_MEMORY_SCOPE_AGENT) < tgt)
                __builtin_amdgcn_s_sleep(1);
        }
        __syncthreads();   // S7: release
        #pragma unroll
        for (int j = 1; j < 4; ++j) {          // gather peers' m'
            int q = (p + j) & 3;
            u64 v = __hip_atomic_load((const u64*)&mbuf[xr * MDIM + 128 * q + ec],
                                      __ATOMIC_RELAXED, __HIP_MEMORY_SCOPE_AGENT);
            *(u64*)&mlds[xr][128 * q + ec] = v;
        }
    }
    __syncthreads();

    // ---- epilogue: out cols [32p, 32p+32), waves 0..1 ----
    if (w < 2) {
        const int oc = 32 * p + 16 * w + l15;
        const __bf16* ro = WO + (size_t)oc * MDIM;
        f32x4 oe = {0,0,0,0}, oo = {0,0,0,0};
        #pragma unroll
        for (int kk = 0; kk < 16; ++kk) {
            bf16x8 am = *(const bf16x8*)&mlds[l15][kk * 32 + koff];
            bf16x8 bw = *(const bf16x8*)&ro[kk * 32 + koff];
            if (kk & 1) oo = mfma16(am, bw, oo); else oe = mfma16(am, bw, oe);
        }
        f32x4 oacc = oe + oo;
        const float bo = bout[oc];
        #pragma unroll
        for (int r = 0; r < 4; ++r)
            out[(size_t)(row0 + 4 * l4 + r) * ODIM + oc] = oacc[r] + bo;
    }
}

extern "C" void kernel_launch(void* const* d_in, const int* in_sizes, int n_in,
                              void* d_out, int out_size, void* d_ws, size_t ws_size,
                              hipStream_t stream)
{
    const float* x    = (const float*)d_in[0];
    const float* m0   = (const float*)d_in[1];
    const float* Wi2f = (const float*)d_in[2];
    const float* bi2f = (const float*)d_in[3];
    const float* Wm2f = (const float*)d_in[4];
    const float* bm2f = (const float*)d_in[5];
    const float* Wf2m = (const float*)d_in[6];
    const float* bf2m = (const float*)d_in[7];
    const float* Wm2m = (const float*)d_in[8];
    const float* bm2m = (const float*)d_in[9];
    const float* Wout = (const float*)d_in[10];
    const float* bout = (const float*)d_in[11];

    char* ws = (char*)d_ws;
    __bf16* WI  = (__bf16*)(ws + WS_WI);
    __bf16* W2F = (__bf16*)(ws + WS_W2F);
    __bf16* W2M = (__bf16*)(ws + WS_W2M);
    __bf16* WF2 = (__bf16*)(ws + WS_WF2);
    __bf16* WO  = (__bf16*)(ws + WS_WO);
    float*  b1  = (float*)(ws + WS_B1);
    float*  b23 = (float*)(ws + WS_B23);
    u32*    ctr = (u32*)(ws + WS_CTR);
    __bf16* fb  = (__bf16*)(ws + WS_FBUF);
    __bf16* mb  = (__bf16*)(ws + WS_MBUF);

    const int prep_total = N_WI + N_W2F + N_W2M + N_WF2 + N_WO + FDIM + MDIM + NGRP * 64;
    lmn_prep<<<(prep_total + 255) / 256, 256, 0, stream>>>(
        Wi2f, Wm2f, Wm2m, Wf2m, Wout, bi2f, bm2f, bf2m, bm2m,
        WI, W2F, W2M, WF2, WO, b1, b23, ctr);

    lmn_scan<<<NCU * NGRP, 512, 0, stream>>>(
        x, m0, WI, W2F, W2M, WF2, WO, b1, b23, bout, ctr, fb, mb, (float*)d_out);
}

// Round 5
// 2411.275 us; speedup vs baseline: 9.8580x; 1.2939x over previous
//
#include <hip/hip_runtime.h>
#include <hip/hip_bf16.h>

typedef __bf16 bf16x8 __attribute__((ext_vector_type(8)));
typedef __bf16 bf16x4 __attribute__((ext_vector_type(4)));
typedef float  f32x4  __attribute__((ext_vector_type(4)));
typedef unsigned int u32;
typedef unsigned long long u64;

static __device__ __forceinline__ f32x4 mfma16(bf16x8 a, bf16x8 b, f32x4 c) {
    return __builtin_amdgcn_mfma_f32_16x16x32_bf16(a, b, c, 0, 0, 0);
}
static __device__ __forceinline__ f32x4 mfma16v(bf16x8 a, f32x4 bw, f32x4 c) {
    return mfma16(a, __builtin_bit_cast(bf16x8, bw), c);
}

#define TLEN 512
#define IDIM 128
#define FDIM 512
#define MDIM 512
#define ODIM 128
#define BC   16      // batch rows per group
#define NGRP 16      // batch groups
#define NCU  8       // WGs per group; CU p owns 64 F-cols + 64 M-cols
#define PSTR 536     // LDS stride (bf16): 1072B -> 16B aligned, 2-way banks
#define XSTR 136

// ---- workspace byte offsets ----
#define WS_WI   0
#define WS_W2F  (WS_WI  + FDIM*IDIM*2)
#define WS_W2M  (WS_W2F + FDIM*MDIM*2)
#define WS_WF2  (WS_W2M + MDIM*MDIM*2)
#define WS_WO   (WS_WF2 + MDIM*FDIM*2)
#define WS_B1   (WS_WO  + ODIM*MDIM*2)
#define WS_B23  (WS_B1  + FDIM*4)
#define WS_CTR  (WS_B23 + MDIM*4)
#define WS_FBUF (WS_CTR + NGRP*64*4)
#define WS_MBUF (WS_FBUF + NGRP*BC*FDIM*2)

#define N_WI  (FDIM*IDIM)
#define N_W2F (FDIM*MDIM)
#define N_W2M (MDIM*MDIM)
#define N_WF2 (MDIM*FDIM)
#define N_WO  (ODIM*MDIM)

__global__ __launch_bounds__(256) void lmn_prep(
    const float* __restrict__ Wi2f, const float* __restrict__ Wm2f,
    const float* __restrict__ Wm2m, const float* __restrict__ Wf2m,
    const float* __restrict__ Wout,
    const float* __restrict__ bi2f, const float* __restrict__ bm2f,
    const float* __restrict__ bf2m, const float* __restrict__ bm2m,
    __bf16* __restrict__ WI, __bf16* __restrict__ W2F, __bf16* __restrict__ W2M,
    __bf16* __restrict__ WF2, __bf16* __restrict__ WO,
    float* __restrict__ b1, float* __restrict__ b23, u32* __restrict__ ctrs)
{
    int i = blockIdx.x * 256 + threadIdx.x;
    if (i < N_WI)  { WI[i]  = (__bf16)Wi2f[i]; return; }  i -= N_WI;
    if (i < N_W2F) { W2F[i] = (__bf16)Wm2f[i]; return; }  i -= N_W2F;
    if (i < N_W2M) { W2M[i] = (__bf16)Wm2m[i]; return; }  i -= N_W2M;
    if (i < N_WF2) { WF2[i] = (__bf16)Wf2m[i]; return; }  i -= N_WF2;
    if (i < N_WO)  { WO[i]  = (__bf16)Wout[i]; return; }  i -= N_WO;
    if (i < FDIM)  { b1[i]  = bi2f[i] + bm2f[i]; return; } i -= FDIM;
    if (i < MDIM)  { b23[i] = bf2m[i] + bm2m[i]; return; } i -= MDIM;
    if (i < NGRP * 64) { ctrs[i] = 0u; return; }
}

// ---------------------------------------------------------------------------
// Scan: 128 WGs x 512 threads (8 waves, 2/SIMD). Group g = 8 WGs (same XCD
// class under round-robin: bid = 16p + g). CU p owns F/M cols [64p,64p+64).
// Wave roles: w<4 -> G1 (f = tanh(x@Wi2f + m@Wm2f + b1)), w>=4 -> G23
// (m' = m@Wm2m + f@Wf2m + b23). Each wave holds exactly 32 weight frags
// (wA[16] + wB[16] = 128 VGPR) -> fits the 256-reg budget, no spill.
// The m-loop (wA) is IDENTICAL code for both roles -> uniform barriers.
// Weight k-frags rotated by 2p so own-block (frags 2p,2p+1) sits at idx 0,1:
// own-block MFMAs for step t+1 execute inside the barrier RTT windows.
// ---------------------------------------------------------------------------
__global__ __launch_bounds__(512, 2) void lmn_scan(
    const float* __restrict__ x, const float* __restrict__ m0,
    const __bf16* __restrict__ WI, const __bf16* __restrict__ W2F,
    const __bf16* __restrict__ W2M, const __bf16* __restrict__ WF2,
    const __bf16* __restrict__ WO,
    const float* __restrict__ b1, const float* __restrict__ b23,
    const float* __restrict__ bout,
    u32* __restrict__ ctrs, __bf16* __restrict__ fbuf_all,
    __bf16* __restrict__ mbuf_all, float* __restrict__ out)
{
    __shared__ __bf16 mlds[BC][PSTR];
    __shared__ __bf16 flds[BC][PSTR];
    __shared__ __bf16 xlds[2][BC][XSTR];

    const int tid  = threadIdx.x;
    const int lane = tid & 63;
    const int w    = tid >> 6;        // 0..7
    const int l15  = lane & 15;
    const int l4   = lane >> 4;
    const int koff = 8 * l4;
    const bool isG1 = (w < 4);

    const int b = blockIdx.x;
    const int g = b & 15;             // group (members at bid=16p+g share XCD class)
    const int p = b >> 4;             // 0..7 position in group
    const int row0 = g * BC;

    u32*    ctr  = ctrs + g * 64;
    __bf16* fbuf = fbuf_all + (size_t)g * BC * FDIM;
    __bf16* mbuf = mbuf_all + (size_t)g * BC * MDIM;

    const int c0 = 64 * p + 16 * (w & 3) + l15;  // lane's output column

    // ---- resident weights: 32 frags = 128 VGPR per lane ----
    f32x4 wA[16], wB[16];
    {
        const __bf16* rA = (isG1 ? W2F : W2M) + (size_t)c0 * MDIM;
        #pragma unroll
        for (int j = 0; j < 16; ++j)
            wA[j] = *(const f32x4*)&rA[((2 * p + j) & 15) * 32 + koff];
        if (isG1) {
            const __bf16* rB = WI + (size_t)c0 * IDIM;
            #pragma unroll
            for (int j = 0; j < 4; ++j) wB[j] = *(const f32x4*)&rB[j * 32 + koff];
            #pragma unroll
            for (int j = 4; j < 16; ++j) wB[j] = f32x4{0, 0, 0, 0};
        } else {
            const __bf16* rB = WF2 + (size_t)c0 * FDIM;
            #pragma unroll
            for (int j = 0; j < 16; ++j)
                wB[j] = *(const f32x4*)&rB[((2 * p + j) & 15) * 32 + koff];
        }
    }
    const float br = isG1 ? b1[c0] : b23[c0];

    // ---- init LDS: full m0, x[0] ----
    for (int u = tid; u < BC * MDIM / 4; u += 512) {
        int r = u >> 7, c = (u & 127) * 4;
        float4 v = *(const float4*)&m0[(size_t)(row0 + r) * MDIM + c];
        *(bf16x4*)&mlds[r][c] = bf16x4{(__bf16)v.x, (__bf16)v.y, (__bf16)v.z, (__bf16)v.w};
    }
    {
        int r = tid >> 5, c = (tid & 31) * 4;
        float4 v = *(const float4*)&x[(size_t)(row0 + r) * TLEN * IDIM + c];
        *(bf16x4*)&xlds[0][r][c] = bf16x4{(__bf16)v.x, (__bf16)v.y, (__bf16)v.z, (__bf16)v.w};
    }
    __syncthreads();

    // ---- seed acc for t=0: x-part (G1) + own-block m-part (uniform) ----
    f32x4 accE = {0, 0, 0, 0}, accO = {0, 0, 0, 0};
    if (isG1) {
        #pragma unroll
        for (int j = 0; j < 4; ++j) {
            bf16x8 ax = *(const bf16x8*)&xlds[0][l15][j * 32 + koff];
            if (j & 1) accO = mfma16v(ax, wB[j], accO);
            else       accE = mfma16v(ax, wB[j], accE);
        }
    }
    #pragma unroll
    for (int j = 0; j < 2; ++j) {
        bf16x8 am = *(const bf16x8*)&mlds[l15][((2 * p + j) & 15) * 32 + koff];
        if (j & 1) accO = mfma16v(am, wA[j], accO);
        else       accE = mfma16v(am, wA[j], accE);
    }

    for (int t = 0; t < TLEN; ++t) {
        // ---- A-phase (uniform): 14 peer m k-frags ----
        #pragma unroll
        for (int j = 2; j < 16; ++j) {
            bf16x8 am = *(const bf16x8*)&mlds[l15][((2 * p + j) & 15) * 32 + koff];
            if (j & 1) accO = mfma16v(am, wA[j], accO);
            else       accE = mfma16v(am, wA[j], accE);
        }
        if (isG1) {                   // f = tanh(pre + b1) -> own cols of flds
            f32x4 fa = accE + accO;
            #pragma unroll
            for (int r = 0; r < 4; ++r)
                flds[4 * l4 + r][c0] = (__bf16)tanhf(fa[r] + br);
        }
        __syncthreads();              // S1: f-own in LDS

        if (tid < 256) {              // export f own block (256 u64)
            int rr = tid >> 4, c4 = (tid & 15) << 2;
            u64 v = *(const u64*)&flds[rr][64 * p + c4];
            __hip_atomic_store((u64*)&fbuf[rr * FDIM + 64 * p + c4], v,
                               __ATOMIC_RELAXED, __HIP_MEMORY_SCOPE_AGENT);
        }
        asm volatile("s_waitcnt vmcnt(0)" ::: "memory");
        __syncthreads();              // S2: exports drained
        if (tid == 0)                 // arrive A
            __hip_atomic_fetch_add(ctr, 1u, __ATOMIC_RELAXED, __HIP_MEMORY_SCOPE_AGENT);

        // RTT window A: stage x_{t+1} (G1 threads) + own-block G3 (G23 waves)
        if (tid < 256 && t + 1 < TLEN) {
            int rr = tid >> 4, c8 = (tid & 15) << 3;
            const float* xs = &x[((size_t)(row0 + rr) * TLEN + (t + 1)) * IDIM + c8];
            float4 v0 = ((const float4*)xs)[0], v1 = ((const float4*)xs)[1];
            *(bf16x8*)&xlds[(t + 1) & 1][rr][c8] =
                bf16x8{(__bf16)v0.x, (__bf16)v0.y, (__bf16)v0.z, (__bf16)v0.w,
                       (__bf16)v1.x, (__bf16)v1.y, (__bf16)v1.z, (__bf16)v1.w};
        }
        if (!isG1) {
            #pragma unroll
            for (int j = 0; j < 2; ++j) {
                bf16x8 af = *(const bf16x8*)&flds[l15][((2 * p + j) & 15) * 32 + koff];
                if (j & 1) accO = mfma16v(af, wB[j], accO);
                else       accE = mfma16v(af, wB[j], accE);
            }
        }
        if (tid == 0) {               // wait A
            u32 tgt = 16u * (u32)t + 8u;
            while (__hip_atomic_load(ctr, __ATOMIC_RELAXED, __HIP_MEMORY_SCOPE_AGENT) < tgt)
                __builtin_amdgcn_s_sleep(1);
        }
        __syncthreads();              // S3: release A
        for (int s = tid; s < 1792; s += 512) {   // gather peers' f (14KB)
            int j = 1 + (s >> 8);
            int k = s & 255;
            int q = (p + j) & 7;
            int rr = k >> 4, c4 = (k & 15) << 2;
            u64 v = __hip_atomic_load((const u64*)&fbuf[rr * FDIM + 64 * q + c4],
                                      __ATOMIC_RELAXED, __HIP_MEMORY_SCOPE_AGENT);
            *(u64*)&flds[rr][64 * q + c4] = v;
        }
        __syncthreads();              // S4: flds full

        // ---- B-phase ----
        if (!isG1) {                  // peer G3 + m' write
            #pragma unroll
            for (int j = 2; j < 16; ++j) {
                bf16x8 af = *(const bf16x8*)&flds[l15][((2 * p + j) & 15) * 32 + koff];
                if (j & 1) accO = mfma16v(af, wB[j], accO);
                else       accE = mfma16v(af, wB[j], accE);
            }
            f32x4 ma = accE + accO;
            #pragma unroll
            for (int r = 0; r < 4; ++r)
                mlds[4 * l4 + r][c0] = (__bf16)(ma[r] + br);
            accE = f32x4{0, 0, 0, 0}; accO = f32x4{0, 0, 0, 0};
        } else {                      // reset + x-part seed for t+1
            accE = f32x4{0, 0, 0, 0}; accO = f32x4{0, 0, 0, 0};
            if (t + 1 < TLEN) {
                #pragma unroll
                for (int j = 0; j < 4; ++j) {
                    bf16x8 ax = *(const bf16x8*)&xlds[(t + 1) & 1][l15][j * 32 + koff];
                    if (j & 1) accO = mfma16v(ax, wB[j], accO);
                    else       accE = mfma16v(ax, wB[j], accE);
                }
            }
        }
        __syncthreads();              // S5: m'-own in LDS

        if (tid >= 256) {             // export m' own block
            int u = tid - 256;
            int rr = u >> 4, c4 = (u & 15) << 2;
            u64 v = *(const u64*)&mlds[rr][64 * p + c4];
            __hip_atomic_store((u64*)&mbuf[rr * MDIM + 64 * p + c4], v,
                               __ATOMIC_RELAXED, __HIP_MEMORY_SCOPE_AGENT);
        }
        asm volatile("s_waitcnt vmcnt(0)" ::: "memory");
        __syncthreads();              // S6: exports drained
        if (tid == 0)                 // arrive B
            __hip_atomic_fetch_add(ctr, 1u, __ATOMIC_RELAXED, __HIP_MEMORY_SCOPE_AGENT);

        // RTT window B: own-block seed for t+1 (uniform: m-part for G1, G2 for G23)
        if (t + 1 < TLEN) {
            #pragma unroll
            for (int j = 0; j < 2; ++j) {
                bf16x8 am = *(const bf16x8*)&mlds[l15][((2 * p + j) & 15) * 32 + koff];
                if (j & 1) accO = mfma16v(am, wA[j], accO);
                else       accE = mfma16v(am, wA[j], accE);
            }
        }
        if (tid == 0) {               // wait B
            u32 tgt = 16u * (u32)t + 16u;
            while (__hip_atomic_load(ctr, __ATOMIC_RELAXED, __HIP_MEMORY_SCOPE_AGENT) < tgt)
                __builtin_amdgcn_s_sleep(1);
        }
        __syncthreads();              // S7: release B
        for (int s = tid; s < 1792; s += 512) {   // gather peers' m'
            int j = 1 + (s >> 8);
            int k = s & 255;
            int q = (p + j) & 7;
            int rr = k >> 4, c4 = (k & 15) << 2;
            u64 v = __hip_atomic_load((const u64*)&mbuf[rr * MDIM + 64 * q + c4],
                                      __ATOMIC_RELAXED, __HIP_MEMORY_SCOPE_AGENT);
            *(u64*)&mlds[rr][64 * q + c4] = v;
        }
        __syncthreads();              // S8: mlds = m_{t+1} full
    }

    // ---- epilogue: group rep (p==0) computes out = m_T @ Wout^T + bout ----
    if (p == 0) {
        const int oc = 16 * w + l15;
        const __bf16* ro = WO + (size_t)oc * MDIM;
        f32x4 oe = {0, 0, 0, 0}, oo = {0, 0, 0, 0};
        #pragma unroll
        for (int j = 0; j < 16; ++j) {
            bf16x8 am = *(const bf16x8*)&mlds[l15][j * 32 + koff];
            bf16x8 bw = *(const bf16x8*)&ro[j * 32 + koff];
            if (j & 1) oo = mfma16(am, bw, oo); else oe = mfma16(am, bw, oe);
        }
        f32x4 oa = oe + oo;
        const float bo = bout[oc];
        #pragma unroll
        for (int r = 0; r < 4; ++r)
            out[(size_t)(row0 + 4 * l4 + r) * ODIM + oc] = oa[r] + bo;
    }
}

extern "C" void kernel_launch(void* const* d_in, const int* in_sizes, int n_in,
                              void* d_out, int out_size, void* d_ws, size_t ws_size,
                              hipStream_t stream)
{
    const float* x    = (const float*)d_in[0];
    const float* m0   = (const float*)d_in[1];
    const float* Wi2f = (const float*)d_in[2];
    const float* bi2f = (const float*)d_in[3];
    const float* Wm2f = (const float*)d_in[4];
    const float* bm2f = (const float*)d_in[5];
    const float* Wf2m = (const float*)d_in[6];
    const float* bf2m = (const float*)d_in[7];
    const float* Wm2m = (const float*)d_in[8];
    const float* bm2m = (const float*)d_in[9];
    const float* Wout = (const float*)d_in[10];
    const float* bout = (const float*)d_in[11];

    char* ws = (char*)d_ws;
    __bf16* WI  = (__bf16*)(ws + WS_WI);
    __bf16* W2F = (__bf16*)(ws + WS_W2F);
    __bf16* W2M = (__bf16*)(ws + WS_W2M);
    __bf16* WF2 = (__bf16*)(ws + WS_WF2);
    __bf16* WO  = (__bf16*)(ws + WS_WO);
    float*  b1  = (float*)(ws + WS_B1);
    float*  b23 = (float*)(ws + WS_B23);
    u32*    ctr = (u32*)(ws + WS_CTR);
    __bf16* fb  = (__bf16*)(ws + WS_FBUF);
    __bf16* mb  = (__bf16*)(ws + WS_MBUF);

    const int prep_total = N_WI + N_W2F + N_W2M + N_WF2 + N_WO + FDIM + MDIM + NGRP * 64;
    lmn_prep<<<(prep_total + 255) / 256, 256, 0, stream>>>(
        Wi2f, Wm2f, Wm2m, Wf2m, Wout, bi2f, bm2f, bf2m, bm2m,
        WI, W2F, W2M, WF2, WO, b1, b23, ctr);

    lmn_scan<<<NGRP * NCU, 512, 0, stream>>>(
        x, m0, WI, W2F, W2M, WF2, WO, b1, b23, bout, ctr, fb, mb, (float*)d_out);
}